// Round 10
// baseline (200.108 us; speedup 1.0000x reference)
//
#include <hip/hip_runtime.h>
#include <math.h>

#define NB 8192     // histogram bins: loss float bits >> 19 (sign+exp+4 mantissa bits)
#define VEC 8       // float4 per array per thread (32 elements/thread)

// loss = max(x,0) - x*t + log1p(exp(-|x|)) >= 0 ; p = sigmoid(x)
__device__ __forceinline__ void elem_f(float x, float t, float& l, float& p) {
    float e = __expf(-fabsf(x));
    l = fmaxf(x, 0.f) - x * t + __logf(1.f + e);
    float r = __builtin_amdgcn_rcpf(1.f + e);
    p = (x >= 0.f) ? r : e * r;
}

// ---------- k0: ONE full pass: bit-histogram (count + weighted sum) + dice sums ----------
// 64 KB LDS -> 2 blocks/CU; (256,2) -> 256-VGPR budget so all 16 dwordx4 pre-issue.
__global__ __launch_bounds__(256, 2) void main_kernel(
    const float4* __restrict__ x4, const float4* __restrict__ t4,
    unsigned* __restrict__ Hc, float* __restrict__ Hw,
    float* __restrict__ q0, float* __restrict__ q1, float* __restrict__ q2,
    const float* __restrict__ xg, const float* __restrict__ tg,
    int n, int n4)
{
    __shared__ unsigned lc[NB];   // 32 KB counts
    __shared__ float    lw[NB];   // 32 KB weighted sums
    for (int i = threadIdx.x; i < NB; i += 256) { lc[i] = 0u; lw[i] = 0.f; }

    int base = blockIdx.x * (256 * VEC) + threadIdx.x;
    bool full = (blockIdx.x + 1) * (256 * VEC) <= n4;   // block-uniform

    // pre-issue all streaming loads (independent of the LDS zeroing)
    float4 xv[VEC], tv[VEC];
    if (full) {
        #pragma unroll
        for (int j = 0; j < VEC; ++j) xv[j] = x4[base + j * 256];
        #pragma unroll
        for (int j = 0; j < VEC; ++j) tv[j] = t4[base + j * 256];
    }
    __syncthreads();               // LDS zero complete

    float sp = 0.f, spt = 0.f, st = 0.f;
    if (full) {
        #pragma unroll
        for (int j = 0; j < VEC; ++j) {
            float xs[4] = {xv[j].x, xv[j].y, xv[j].z, xv[j].w};
            float ts[4] = {tv[j].x, tv[j].y, tv[j].z, tv[j].w};
            #pragma unroll
            for (int c = 0; c < 4; ++c) {
                float l, p;
                elem_f(xs[c], ts[c], l, p);
                sp += p; spt += p * ts[c]; st += ts[c];
                unsigned b = __float_as_uint(l) >> 19;
                atomicAdd(&lc[b], 1u);       // ds_add_u32
                atomicAdd(&lw[b], l);        // ds_add_f32
            }
        }
    } else {
        for (int j = 0; j < VEC; ++j) {
            int idx = base + j * 256;
            if (idx >= n4) continue;
            float4 xq = x4[idx], tq = t4[idx];
            float xs[4] = {xq.x, xq.y, xq.z, xq.w};
            float ts[4] = {tq.x, tq.y, tq.z, tq.w};
            #pragma unroll
            for (int c = 0; c < 4; ++c) {
                float l, p;
                elem_f(xs[c], ts[c], l, p);
                sp += p; spt += p * ts[c]; st += ts[c];
                unsigned b = __float_as_uint(l) >> 19;
                atomicAdd(&lc[b], 1u);
                atomicAdd(&lw[b], l);
            }
        }
    }
    // scalar tail (n % 4) on block 0
    int tail0 = n4 << 2;
    if (blockIdx.x == 0 && threadIdx.x < (n - tail0)) {
        float x = xg[tail0 + threadIdx.x], t = tg[tail0 + threadIdx.x];
        float l, p;
        elem_f(x, t, l, p);
        sp += p; spt += p * t; st += t;
        unsigned b = __float_as_uint(l) >> 19;
        atomicAdd(&lc[b], 1u);
        atomicAdd(&lw[b], l);
    }

    // merge block-local histograms (only nonzero bins)
    __syncthreads();
    for (int i = threadIdx.x; i < NB; i += 256) {
        unsigned c = lc[i];
        if (c) { atomicAdd(&Hc[i], c); atomicAdd(&Hw[i], lw[i]); }
    }

    // wave -> block reduce, ONE private slot write per block (no contended atomics)
    #pragma unroll
    for (int off = 32; off; off >>= 1) {
        sp  += __shfl_down(sp,  off);
        spt += __shfl_down(spt, off);
        st  += __shfl_down(st,  off);
    }
    __shared__ float rs[4][3];
    int w = threadIdx.x >> 6;
    if ((threadIdx.x & 63) == 0) {
        rs[w][0] = sp; rs[w][1] = spt; rs[w][2] = st;
    }
    __syncthreads();
    if (threadIdx.x == 0) {
        float a0 = 0, a1 = 0, a2 = 0;
        #pragma unroll
        for (int i = 0; i < 4; ++i) { a0 += rs[i][0]; a1 += rs[i][1]; a2 += rs[i][2]; }
        q0[blockIdx.x] = a0; q1[blockIdx.x] = a1; q2[blockIdx.x] = a2;
    }
}

// ---------- k1: reduce partials + top-k from histogram + emit scalar ----------
__global__ __launch_bounds__(1024) void final_kernel(
    const unsigned* __restrict__ Hc, const float* __restrict__ Hw,
    const float* __restrict__ q0, const float* __restrict__ q1,
    const float* __restrict__ q2, int nblocks,
    float* __restrict__ out, long long k)
{
    __shared__ double red[16][3];
    __shared__ double fin[3];

    double a0 = 0, a1 = 0, a2 = 0;
    for (int i = threadIdx.x; i < nblocks; i += 1024) {
        a0 += (double)q0[i]; a1 += (double)q1[i]; a2 += (double)q2[i];
    }
    #pragma unroll
    for (int off = 32; off; off >>= 1) {
        a0 += __shfl_down(a0, off);
        a1 += __shfl_down(a1, off);
        a2 += __shfl_down(a2, off);
    }
    int w = threadIdx.x >> 6;
    if ((threadIdx.x & 63) == 0) { red[w][0] = a0; red[w][1] = a1; red[w][2] = a2; }
    __syncthreads();
    if (threadIdx.x == 0) {
        double f0 = 0, f1 = 0, f2 = 0;
        for (int i = 0; i < 16; ++i) { f0 += red[i][0]; f1 += red[i][1]; f2 += red[i][2]; }
        fin[0] = f0; fin[1] = f1; fin[2] = f2;
    }
    __syncthreads();
    if (threadIdx.x >= 64) return;

    int lane = threadIdx.x;
    double SP = fin[0], SPT = fin[1], ST = fin[2];
    double dice_part = 0.5 * (1.0 - (2.0 * SPT + 1e-6) / ((SP + ST) + 1e-6));

    // lane owns 128 consecutive bins [lane*128, lane*128+128); read straight from
    // global (L2-resident, independent loads -> unrolled/batched by compiler).
    int b0 = lane << 7;
    unsigned long long cchunk = 0;
    double wchunk = 0.0;
    for (int j = 0; j < 128; ++j) {
        cchunk += Hc[b0 + j];
        wchunk += (double)Hw[b0 + j];
    }
    // inclusive suffix-scan across lanes (lane 63 holds the top bins)
    unsigned long long cs = cchunk;
    double wsum = wchunk;
    #pragma unroll
    for (int off = 1; off < 64; off <<= 1) {
        unsigned long long cv = __shfl_down(cs, off);
        double wv = __shfl_down(wsum, off);
        if (lane + off < 64) { cs += cv; wsum += wv; }
    }
    unsigned long long c = cs - cchunk;    // count strictly above my chunk
    double wacc = wsum - wchunk;           // loss-sum strictly above my chunk

    for (int j = 127; j >= 0; --j) {
        unsigned b = (unsigned)(b0 + j);
        unsigned h = Hc[b];
        float wv = Hw[b];
        if (h && c < (unsigned long long)k && (unsigned long long)k <= c + h) {
            long long k2 = k - (long long)c;           // 1..h taken from this bin
            double lo = (double)__uint_as_float(b << 19);
            double hi = (double)__uint_as_float((b + 1) << 19);
            double binw = hi - lo;
            double m = (double)wv / (double)h;          // empirical bin mean
            // top-k2 of h values modeled uniform, centered on the empirical mean
            double est = m + binw * (double)(h - k2) / (2.0 * (double)h);
            double sum_top = wacc + (double)k2 * est;
            double bce = sum_top / (double)k;
            out[0] = (float)(bce + dice_part);
        }
        c += h;
        wacc += (double)wv;
    }
}

extern "C" void kernel_launch(void* const* d_in, const int* in_sizes, int n_in,
                              void* d_out, int out_size, void* d_ws, size_t ws_size,
                              hipStream_t stream)
{
    const float* x = (const float*)d_in[0];
    const float* t = (const float*)d_in[1];
    float* out = (float*)d_out;
    int n = in_sizes[0];
    int n4 = n >> 2;
    long long k = (long long)((double)n * 0.2);   // Python int() truncation
    if (k < 1) k = 1;

    int tilesz = 256 * VEC;                       // float4 per tile
    int grid = (n4 + tilesz - 1) / tilesz;
    if (grid < 1) grid = 1;

    unsigned char* ws = (unsigned char*)d_ws;
    unsigned* Hc = (unsigned*)(ws);               // 32 KB
    float*    Hw = (float*)(ws + 32768);          // 32 KB
    size_t po = 65536;                            // partials base
    size_t pstride = (((size_t)grid * 4) + 255) & ~(size_t)255;
    float* q0 = (float*)(ws + po);
    float* q1 = (float*)(ws + po + pstride);
    float* q2 = (float*)(ws + po + 2 * pstride);

    hipMemsetAsync(d_ws, 0, 65536, stream);       // Hc + Hw

    main_kernel<<<grid, 256, 0, stream>>>((const float4*)x, (const float4*)t,
                                          Hc, Hw, q0, q1, q2, x, t, n, n4);
    final_kernel<<<1, 1024, 0, stream>>>(Hc, Hw, q0, q1, q2, grid, out, k);
}